// Round 1
// baseline (642.691 us; speedup 1.0000x reference)
//
#include <hip/hip_runtime.h>
#include <math.h>

// ---------------- problem constants ----------------
constexpr int Bn  = 128;      // batch
constexpr int Kd  = 65536;    // magnitude dim (first half of feats; phase half is zeros)
constexpr int F1  = 128;
constexpr int F2  = 64;
constexpr int NM  = 3;        // number of ops matrices
constexpr int Qd  = 256;
constexpr int NCH = 256;      // split-K chunks for big GEMM
constexpr int KC  = 256;      // k per chunk
constexpr int MSZ = 256 * 256;

// quintic (Muon) Newton-Schulz coefficients
#define QA 3.4445f
#define QB (-4.7750f)
#define QC 2.0315f

// ---------------- ws layout (float offsets) ----------------
constexpr size_t OFF_H1P = 0;                                  // 256*128*128 = 4,194,304
constexpr size_t OFF_H1  = OFF_H1P + (size_t)NCH * Bn * F1;    // 16384
constexpr size_t OFF_SEL = OFF_H1 + (size_t)Bn * F1;           // 128 ints
constexpr size_t OFF_SN  = OFF_SEL + 128;                      // 16
constexpr size_t OFF_XA  = OFF_SN + 16;
constexpr size_t OFF_XB  = OFF_XA + (size_t)NM * MSZ;
constexpr size_t OFF_AM  = OFF_XB + (size_t)NM * MSZ;
constexpr size_t OFF_YM  = OFF_AM + (size_t)NM * MSZ;
// total ≈ 20 MB of ws

// ---------------- K1: split-K magnitude GEMM ----------------
// h1p[ch][b][j] = sum_{k in chunk ch} |sp[b][k]| * W1[j][k]
__global__ __launch_bounds__(256) void k_gemm1(const float* __restrict__ sp,
                                               const float* __restrict__ W1,
                                               float* __restrict__ h1p) {
  __shared__ float As[128][33];
  __shared__ float Ws[128][33];
  const int t  = threadIdx.x;
  const int ch = blockIdx.x;
  const int k0 = ch * KC;
  const int r0 = (t >> 4) * 8;   // batch-row tile base
  const int cw = t & 15;         // col lane; cols cw + 16*cc (bank-conflict-free)
  float acc[8][8];
#pragma unroll
  for (int r = 0; r < 8; ++r)
#pragma unroll
    for (int c = 0; c < 8; ++c) acc[r][c] = 0.f;

  const int kk = t & 31, bq = t >> 5;
  for (int kt = 0; kt < 8; ++kt) {
    __syncthreads();
    const int kb = k0 + kt * 32 + kk;
#pragma unroll
    for (int bb = bq; bb < 128; bb += 8) {
      As[bb][kk] = fabsf(sp[bb * Kd + kb]);
      Ws[bb][kk] = W1[bb * (2 * Kd) + kb];   // W1 row stride = 131072
    }
    __syncthreads();
#pragma unroll
    for (int q = 0; q < 32; ++q) {
      float a[8], w[8];
#pragma unroll
      for (int r = 0; r < 8; ++r) a[r] = As[r0 + r][q];
#pragma unroll
      for (int c = 0; c < 8; ++c) w[c] = Ws[cw + 16 * c][q];
#pragma unroll
      for (int r = 0; r < 8; ++r)
#pragma unroll
        for (int c = 0; c < 8; ++c) acc[r][c] += a[r] * w[c];
    }
  }
  float* outp = h1p + (size_t)ch * (Bn * F1);
#pragma unroll
  for (int r = 0; r < 8; ++r)
#pragma unroll
    for (int c = 0; c < 8; ++c)
      outp[(r0 + r) * F1 + cw + 16 * c] = acc[r][c];
}

// ---------------- K1b: reduce partials + bias + relu ----------------
__global__ __launch_bounds__(256) void k_red(const float* __restrict__ h1p,
                                             const float* __restrict__ b1,
                                             float* __restrict__ h1) {
  const int o = blockIdx.x * 256 + threadIdx.x;  // 0..16383
  double s0 = 0, s1 = 0, s2 = 0, s3 = 0;
#pragma unroll 8
  for (int c = 0; c < NCH; c += 4) {
    s0 += (double)h1p[(size_t)(c + 0) * (Bn * F1) + o];
    s1 += (double)h1p[(size_t)(c + 1) * (Bn * F1) + o];
    s2 += (double)h1p[(size_t)(c + 2) * (Bn * F1) + o];
    s3 += (double)h1p[(size_t)(c + 3) * (Bn * F1) + o];
  }
  const float v = (float)(s0 + s1 + s2 + s3) + b1[o & 127];
  h1[o] = fmaxf(v, 0.f);
}

// ---------------- K2: small MLP + syndrome + selection ----------------
__global__ __launch_bounds__(256) void k_mlp(const float* __restrict__ h1,
                                             const float* __restrict__ W2,
                                             const float* __restrict__ b2,
                                             const float* __restrict__ W3,
                                             const float* __restrict__ b3,
                                             int* __restrict__ sel) {
  const int t = threadIdx.x;
  const int b0 = blockIdx.x * 16;  // 8 blocks x 16 batches
  __shared__ float h2s[16 * 64];
  for (int o = t; o < 16 * 64; o += 256) {
    const int bl = o >> 6, j = o & 63;
    const float* hr = h1 + (b0 + bl) * F1;
    const float* wr = W2 + j * F1;
    float s = b2[j];
    for (int k = 0; k < F1; ++k) s += hr[k] * wr[k];
    h2s[o] = fmaxf(s, 0.f);
  }
  __syncthreads();
  if (t < 16) {
    const int b = b0 + t;
    float best = -1.f;
    int bi = 0;
    bool needed = false;
    for (int j = 0; j < 8; ++j) {
      double s = (double)b3[j];
      const float* wr = W3 + j * F2;
      for (int k = 0; k < F2; ++k) s += (double)h2s[t * F2 + k] * (double)wr[k];
      const float a = fabsf((float)s);
      if (a > 1e-4f) needed = true;
      if (a > best) { best = a; bi = j; }   // strict >  => first-max ties, matches argmax
    }
    sel[b] = needed ? (bi % NM) : -1;
  }
}

// ---------------- NS: Frobenius-based scale ----------------
__global__ __launch_bounds__(256) void k_norm(const float* __restrict__ ops,
                                              float* __restrict__ sn) {
  const int m = blockIdx.x, t = threadIdx.x;
  const float* C = ops + (size_t)m * MSZ;
  float acc = 0.f;
  for (int i = t; i < MSZ; i += 256) { const float v = C[i]; acc += v * v; }
  __shared__ float red[256];
  red[t] = acc;
  __syncthreads();
  for (int s = 128; s > 0; s >>= 1) {
    if (t < s) red[t] += red[t + s];
    __syncthreads();
  }
  if (t == 0) sn[m] = 1.f / (0.15f * sqrtf(red[0]));  // 1/(1.2 * 2*||F||/sqrt(256))
}

__global__ __launch_bounds__(256) void k_scale(const float* __restrict__ ops,
                                               const float* __restrict__ sn,
                                               float* __restrict__ X) {
  const int i4 = blockIdx.x * 256 + threadIdx.x;  // 0..49151 float4s
  const int m = i4 >> 14;                          // 16384 f4 per matrix
  const float s = sn[m];
  float4 v = ((const float4*)ops)[i4];
  v.x *= s; v.y *= s; v.z *= s; v.w *= s;
  ((float4*)X)[i4] = v;
}

// ---------------- NS phase kernels (192 blocks = 3 matrices x 64 row-groups) ----------------
// A = X^T X
__global__ __launch_bounds__(256) void k_pA(const float* __restrict__ X,
                                            float* __restrict__ A) {
  const int m = blockIdx.x >> 6, i0 = (blockIdx.x & 63) * 4;
  const int t = threadIdx.x;
  const float* Xm = X + (size_t)m * MSZ;
  float* Am = A + (size_t)m * MSZ;
  __shared__ __align__(16) float cols[256][4];
  const float4 cv = *(const float4*)(Xm + t * 256 + i0);  // X[t][i0..i0+3]
  cols[t][0] = cv.x; cols[t][1] = cv.y; cols[t][2] = cv.z; cols[t][3] = cv.w;
  __syncthreads();
  float a0 = 0, a1 = 0, a2 = 0, a3 = 0;
#pragma unroll 4
  for (int k = 0; k < 256; ++k) {
    const float v = Xm[k * 256 + t];
    const float4 c = *(const float4*)&cols[k][0];
    a0 += c.x * v; a1 += c.y * v; a2 += c.z * v; a3 += c.w * v;
  }
  Am[(i0 + 0) * 256 + t] = a0;
  Am[(i0 + 1) * 256 + t] = a1;
  Am[(i0 + 2) * 256 + t] = a2;
  Am[(i0 + 3) * 256 + t] = a3;
}

// Y = X * A
__global__ __launch_bounds__(256) void k_pY(const float* __restrict__ X,
                                            const float* __restrict__ A,
                                            float* __restrict__ Y) {
  const int m = blockIdx.x >> 6, i0 = (blockIdx.x & 63) * 4;
  const int t = threadIdx.x;
  const float* Xm = X + (size_t)m * MSZ;
  const float* Am = A + (size_t)m * MSZ;
  float* Ym = Y + (size_t)m * MSZ;
  __shared__ __align__(16) float pt[256][4];
#pragma unroll
  for (int r = 0; r < 4; ++r) pt[t][r] = Xm[(i0 + r) * 256 + t];
  __syncthreads();
  float a0 = 0, a1 = 0, a2 = 0, a3 = 0;
#pragma unroll 4
  for (int k = 0; k < 256; ++k) {
    const float v = Am[k * 256 + t];
    const float4 c = *(const float4*)&pt[k][0];
    a0 += c.x * v; a1 += c.y * v; a2 += c.z * v; a3 += c.w * v;
  }
  Ym[(i0 + 0) * 256 + t] = a0;
  Ym[(i0 + 1) * 256 + t] = a1;
  Ym[(i0 + 2) * 256 + t] = a2;
  Ym[(i0 + 3) * 256 + t] = a3;
}

// X' = QA*X + QB*Y + QC*(Y*A)
__global__ __launch_bounds__(256) void k_pX5(const float* __restrict__ X,
                                             const float* __restrict__ Y,
                                             const float* __restrict__ A,
                                             float* __restrict__ Xn) {
  const int m = blockIdx.x >> 6, i0 = (blockIdx.x & 63) * 4;
  const int t = threadIdx.x;
  const float* Xm = X + (size_t)m * MSZ;
  const float* Ym = Y + (size_t)m * MSZ;
  const float* Am = A + (size_t)m * MSZ;
  float* Xo = Xn + (size_t)m * MSZ;
  __shared__ __align__(16) float pt[256][4];
#pragma unroll
  for (int r = 0; r < 4; ++r) pt[t][r] = Ym[(i0 + r) * 256 + t];
  __syncthreads();
  float a0 = 0, a1 = 0, a2 = 0, a3 = 0;
#pragma unroll 4
  for (int k = 0; k < 256; ++k) {
    const float v = Am[k * 256 + t];
    const float4 c = *(const float4*)&pt[k][0];
    a0 += c.x * v; a1 += c.y * v; a2 += c.z * v; a3 += c.w * v;
  }
  Xo[(i0 + 0) * 256 + t] = QA * Xm[(i0 + 0) * 256 + t] + QB * pt[t][0] + QC * a0;
  Xo[(i0 + 1) * 256 + t] = QA * Xm[(i0 + 1) * 256 + t] + QB * pt[t][1] + QC * a1;
  Xo[(i0 + 2) * 256 + t] = QA * Xm[(i0 + 2) * 256 + t] + QB * pt[t][2] + QC * a2;
  Xo[(i0 + 3) * 256 + t] = QA * Xm[(i0 + 3) * 256 + t] + QB * pt[t][3] + QC * a3;
}

// X' = 1.5*X - 0.5*(X*A)
__global__ __launch_bounds__(256) void k_pC(const float* __restrict__ X,
                                            const float* __restrict__ A,
                                            float* __restrict__ Xn) {
  const int m = blockIdx.x >> 6, i0 = (blockIdx.x & 63) * 4;
  const int t = threadIdx.x;
  const float* Xm = X + (size_t)m * MSZ;
  const float* Am = A + (size_t)m * MSZ;
  float* Xo = Xn + (size_t)m * MSZ;
  __shared__ __align__(16) float pt[256][4];
#pragma unroll
  for (int r = 0; r < 4; ++r) pt[t][r] = Xm[(i0 + r) * 256 + t];
  __syncthreads();
  float a0 = 0, a1 = 0, a2 = 0, a3 = 0;
#pragma unroll 4
  for (int k = 0; k < 256; ++k) {
    const float v = Am[k * 256 + t];
    const float4 c = *(const float4*)&pt[k][0];
    a0 += c.x * v; a1 += c.y * v; a2 += c.z * v; a3 += c.w * v;
  }
  Xo[(i0 + 0) * 256 + t] = 1.5f * pt[t][0] - 0.5f * a0;
  Xo[(i0 + 1) * 256 + t] = 1.5f * pt[t][1] - 0.5f * a1;
  Xo[(i0 + 2) * 256 + t] = 1.5f * pt[t][2] - 0.5f * a2;
  Xo[(i0 + 3) * 256 + t] = 1.5f * pt[t][3] - 0.5f * a3;
}

// ---------------- K4: output assembly ----------------
// blocks 0..127: per-batch head update; blocks 128..2175: float4 tail copy
__global__ __launch_bounds__(256) void k_out(const float* __restrict__ sp,
                                             const float* __restrict__ P,
                                             const int* __restrict__ sel,
                                             float* __restrict__ out) {
  const int t = threadIdx.x;
  if (blockIdx.x < 128) {
    const int b = blockIdx.x;
    __shared__ float hd[256];
    hd[t] = sp[(size_t)b * Kd + t];
    __syncthreads();
    const int s = sel[b];
    if (s < 0) {
      out[(size_t)b * Kd + t] = hd[t];
    } else {
      const float4* prow = (const float4*)(P + (size_t)s * MSZ + t * 256);
      float acc = 0.f;
#pragma unroll 8
      for (int j4 = 0; j4 < 64; ++j4) {
        const float4 p = prow[j4];
        acc += p.x * hd[4 * j4 + 0] + p.y * hd[4 * j4 + 1] +
               p.z * hd[4 * j4 + 2] + p.w * hd[4 * j4 + 3];
      }
      out[(size_t)b * Kd + t] = hd[t] + 0.1f * acc;
    }
  } else {
    const int ci = blockIdx.x - 128;  // 0..2047
    const float4* in4 = (const float4*)sp;
    float4* out4 = (float4*)out;
    const int total = Bn * (Kd / 4);  // 2,097,152
    for (int i = ci * 256 + t; i < total; i += 2048 * 256) {
      const int pos = i & ((Kd / 4) - 1);
      if (pos >= Qd / 4) out4[i] = in4[i];
    }
  }
}

// ---------------- host ----------------
extern "C" void kernel_launch(void* const* d_in, const int* in_sizes, int n_in,
                              void* d_out, int out_size, void* d_ws, size_t ws_size,
                              hipStream_t stream) {
  (void)in_sizes; (void)n_in; (void)out_size; (void)ws_size;
  const float* sp = (const float*)d_in[0];
  const float* W1 = (const float*)d_in[1];
  const float* b1 = (const float*)d_in[2];
  const float* W2 = (const float*)d_in[3];
  const float* b2 = (const float*)d_in[4];
  const float* W3 = (const float*)d_in[5];
  const float* b3 = (const float*)d_in[6];
  const float* ops = (const float*)d_in[7];
  float* out = (float*)d_out;
  float* ws = (float*)d_ws;

  float* h1p = ws + OFF_H1P;
  float* h1  = ws + OFF_H1;
  int*   sel = (int*)(ws + OFF_SEL);
  float* sn  = ws + OFF_SN;
  float* Xa  = ws + OFF_XA;
  float* Xb  = ws + OFF_XB;
  float* Am  = ws + OFF_AM;
  float* Ym  = ws + OFF_YM;

  k_gemm1<<<NCH, 256, 0, stream>>>(sp, W1, h1p);
  k_red<<<64, 256, 0, stream>>>(h1p, b1, h1);
  k_mlp<<<8, 256, 0, stream>>>(h1, W2, b2, W3, b3, sel);
  k_norm<<<NM, 256, 0, stream>>>(ops, sn);
  k_scale<<<192, 256, 0, stream>>>(ops, sn, Xa);

  float* X = Xa;
  float* Xn = Xb;
  for (int i = 0; i < 8; ++i) {  // quintic (Muon) iterations
    k_pA<<<192, 256, 0, stream>>>(X, Am);
    k_pY<<<192, 256, 0, stream>>>(X, Am, Ym);
    k_pX5<<<192, 256, 0, stream>>>(X, Ym, Am, Xn);
    float* tmp = X; X = Xn; Xn = tmp;
  }
  for (int i = 0; i < 5; ++i) {  // cubic polish
    k_pA<<<192, 256, 0, stream>>>(X, Am);
    k_pC<<<192, 256, 0, stream>>>(X, Am, Xn);
    float* tmp = X; X = Xn; Xn = tmp;
  }

  k_out<<<128 + 2048, 256, 0, stream>>>(sp, X, sel, out);
}